// Round 1
// baseline (384.983 us; speedup 1.0000x reference)
//
#include <hip/hip_runtime.h>

// Pink-noise 6-pole IIR — single fused kernel, ticket-ordered decoupled lookback.
//   Phase A: per-tile (4096 samples) affine aggregate from the wave-scan totals,
//            published with an agent-scope release flag.
//   Lookback: fold predecessor aggregates with A^4096 (decays below 1e-12 in
//            <=6 tiles -> bounded spin). Ticket ordering makes spins safe
//            under undefined dispatch order.
//   Phase B: per-thread exclusive prefix -> recompute outputs; LDS-transposed
//            coalesced IO (identical to the proven K3 epilogue).

constexpr int kL = 65536;         // samples per channel
constexpr int kTile = 4096;       // samples per block
constexpr int kThr = 256;         // threads per block (4 waves)
constexpr int kChunk = 16;        // samples per thread
constexpr int kTilesPerCh = kL / kTile;  // 16

// XOR swizzle: bank-balances both the chunk-strided (16/thread) and the
// linear float4 access patterns; bijective on [0,4096); preserves 16B align.
__device__ __forceinline__ int swz(int i) {
    return i ^ (((i >> 5) & 7) << 2);
}

__global__ __launch_bounds__(kThr) void pink_fused(
    const float* __restrict__ white, float* __restrict__ pink,
    unsigned int* __restrict__ ticket, unsigned int* __restrict__ flags,
    float* __restrict__ tile_e, int nTiles)
{
    constexpr float A[6] = {0.99886f, 0.99332f, 0.969f, 0.8665f, 0.55f, -0.7616f};
    constexpr float C[6] = {0.0555179f, 0.0750759f, 0.153852f, 0.3104856f, 0.5329522f, -0.016898f};
    constexpr float B6G = 0.115926f, DIRECT = 0.5362f, OUTG = 0.11f;

    __shared__ __align__(16) float buf[kTile];
    __shared__ float swv[6][4];
    __shared__ float sP[6];
    __shared__ unsigned int svb;

    const int tid = threadIdx.x, lane = tid & 63, wave = tid >> 6;

    // Virtual tile id: guarantees every lower id is already dispatched, so
    // the lookback spin below can never deadlock (no dispatch-order assumption).
    if (tid == 0) svb = atomicAdd(ticket, 1u);
    __syncthreads();
    const int blk = (int)svb;
    const size_t base = (size_t)blk * kTile;

    // Coalesced load -> LDS (swizzled).
    const float4* src = (const float4*)(white + base);
    float4 v[4];
    #pragma unroll
    for (int k = 0; k < 4; ++k) v[k] = src[tid + k * kThr];
    #pragma unroll
    for (int k = 0; k < 4; ++k)
        *(float4*)&buf[swz(4 * (tid + k * kThr))] = v[k];

    // Previous white sample for thread 0's b6 (0 at channel start).
    float pw0 = 0.f;
    if (tid == 0 && (blk & (kTilesPerCh - 1)) != 0) pw0 = white[base - 1];

    // Constants: m16=A^16, pmL=(A^16)^lane, Mwv=A^1024.
    float m16[6], pmL[6], Mwv[6];
    #pragma unroll
    for (int p = 0; p < 6; ++p) {
        float q = A[p];
        #pragma unroll
        for (int i = 0; i < 4; ++i) q *= q;          // A^16
        m16[p] = q;
        float pm = 1.f, qq = q;
        #pragma unroll
        for (int b = 0; b < 6; ++b) { if ((lane >> b) & 1) pm *= qq; qq *= qq; }
        pmL[p] = pm;
        Mwv[p] = qq;                                  // (A^16)^64 = A^1024
    }
    __syncthreads();

    float w[kChunk];
    #pragma unroll
    for (int kk = 0; kk < kChunk / 4; ++kk) {
        float4 x = *(const float4*)&buf[swz(kChunk * tid + 4 * kk)];
        w[4*kk] = x.x; w[4*kk+1] = x.y; w[4*kk+2] = x.z; w[4*kk+3] = x.w;
    }
    const float pwl = (tid == 0) ? pw0 : buf[swz(kChunk * tid - 1)];

    // Local scan from zero init.
    float e[6] = {0.f, 0.f, 0.f, 0.f, 0.f, 0.f};
    #pragma unroll
    for (int k = 0; k < kChunk; ++k) {
        const float ww = w[k];
        #pragma unroll
        for (int p = 0; p < 6; ++p) e[p] = fmaf(A[p], e[p], ww * C[p]);
    }

    // Intra-wave affine scan (constant per-round multiplier).
    float mk[6];
    #pragma unroll
    for (int p = 0; p < 6; ++p) mk[p] = m16[p];
    #pragma unroll
    for (int r = 0; r < 6; ++r) {
        const int off = 1 << r;
        float fe[6];
        #pragma unroll
        for (int p = 0; p < 6; ++p) fe[p] = __shfl_up(e[p], off);
        if (lane >= off) {
            #pragma unroll
            for (int p = 0; p < 6; ++p) e[p] = fmaf(mk[p], fe[p], e[p]);
        }
        #pragma unroll
        for (int p = 0; p < 6; ++p) mk[p] *= mk[p];
    }
    float ex[6];
    #pragma unroll
    for (int p = 0; p < 6; ++p) {
        ex[p] = __shfl_up(e[p], 1);
        if (lane == 0) ex[p] = 0.f;
    }
    if (lane == 63) {
        #pragma unroll
        for (int p = 0; p < 6; ++p) swv[p][wave] = e[p];
    }
    __syncthreads();

    // ---- Publish tile aggregate, then lookback for the tile prefix ----
    if (tid == 0) {
        // Block aggregate = fold of the 4 wave totals with Mwv = A^1024.
        #pragma unroll
        for (int p = 0; p < 6; ++p) {
            float t = swv[p][0];
            #pragma unroll
            for (int w2 = 1; w2 < 4; ++w2) t = fmaf(Mwv[p], t, swv[p][w2]);
            tile_e[(size_t)p * nTiles + blk] = t;
        }
        // Release: aggregate stores are visible (agent scope) before the flag.
        __hip_atomic_store(&flags[blk], 1u, __ATOMIC_RELEASE,
                           __HIP_MEMORY_SCOPE_AGENT);

        // Lookback: P = sum_{s<t} (A^4096)^(t-1-s) * agg_s.
        // |A^4096| <= 9.4e-3, so coefficients drop below 1e-12 after <=6 tiles.
        float Pl[6] = {0.f, 0.f, 0.f, 0.f, 0.f, 0.f};
        const int tW = blk & (kTilesPerCh - 1);
        if (tW) {
            float A4k[6], cm[6];
            #pragma unroll
            for (int p = 0; p < 6; ++p) {
                float q = Mwv[p] * Mwv[p]; q *= q;    // A^4096
                A4k[p] = q; cm[p] = 1.f;
            }
            for (int s = tW - 1; s >= 0; --s) {
                const int sb = (blk - tW) + s;
                while (__hip_atomic_load(&flags[sb], __ATOMIC_ACQUIRE,
                                         __HIP_MEMORY_SCOPE_AGENT) == 0u)
                    __builtin_amdgcn_s_sleep(1);
                #pragma unroll
                for (int p = 0; p < 6; ++p) {
                    Pl[p] = fmaf(cm[p], tile_e[(size_t)p * nTiles + sb], Pl[p]);
                    cm[p] *= A4k[p];
                }
                if (cm[0] < 1e-12f) break;   // remaining terms below fp32 noise
            }
        }
        #pragma unroll
        for (int p = 0; p < 6; ++p) sP[p] = Pl[p];
    }
    __syncthreads();

    // Per-thread incoming state: fold tile prefix through previous waves,
    // then apply this lane's exclusive span.
    float b[6];
    #pragma unroll
    for (int p = 0; p < 6; ++p) {
        float X = sP[p];
        #pragma unroll
        for (int w2 = 0; w2 < 3; ++w2)
            if (w2 < wave) X = fmaf(Mwv[p], X, swv[p][w2]);
        b[p] = fmaf(pmL[p], X, ex[p]);
    }
    float b6 = B6G * pwl;

    // Recompute with correct init; outputs overwrite inputs in buf.
    // (All reads of buf happened before the swv barrier — safe.)
    #pragma unroll
    for (int kk = 0; kk < kChunk / 4; ++kk) {
        float4 o;
        float* op = &o.x;
        #pragma unroll
        for (int j = 0; j < 4; ++j) {
            const float ww = w[4*kk + j];
            #pragma unroll
            for (int p = 0; p < 6; ++p) b[p] = fmaf(A[p], b[p], ww * C[p]);
            const float sum = ((b[0]+b[1]) + (b[2]+b[3])) + ((b[4]+b[5]) + b6);
            op[j] = fmaf(DIRECT, ww, sum) * OUTG;
            b6 = B6G * ww;
        }
        *(float4*)&buf[swz(kChunk * tid + 4 * kk)] = o;
    }
    __syncthreads();

    float4* dst = (float4*)(pink + base);
    #pragma unroll
    for (int k = 0; k < 4; ++k)
        dst[tid + k * kThr] = *(const float4*)&buf[swz(4 * (tid + k * kThr))];
}

extern "C" void kernel_launch(void* const* d_in, const int* in_sizes, int n_in,
                              void* d_out, int out_size, void* d_ws, size_t ws_size,
                              hipStream_t stream) {
    const float* white = (const float*)d_in[0];
    float* pink = (float*)d_out;
    const int nTiles = in_sizes[0] / kTile;                // 4096

    // Workspace layout: [ticket(16B pad)][flags: nTiles u32][tile_e: 6*nTiles f32]
    unsigned int* ticket = (unsigned int*)d_ws;
    unsigned int* flags  = ticket + 4;                     // 16 B offset
    float* tile_e = (float*)(flags + nTiles);

    // Reset ticket + flags every launch (workspace is re-poisoned between runs;
    // graph replay re-executes this node).
    hipMemsetAsync(d_ws, 0, 16 + sizeof(unsigned int) * (size_t)nTiles, stream);

    hipLaunchKernelGGL(pink_fused, dim3(nTiles), dim3(kThr), 0, stream,
                       white, pink, ticket, flags, tile_e, nTiles);
}

// Round 2
// 294.894 us; speedup vs baseline: 1.3055x; 1.3055x over previous
//
#include <hip/hip_runtime.h>

// Pink-noise 6-pole IIR — ONE kernel, one block per channel (B=256 = CU count).
// The sequential dependency never leaves the block: each block scans its
// channel in 4 chunks of 16384 samples, carrying the pole state in registers.
//   per chunk: coalesced float4 -> swizzled LDS transpose -> 16-sample local
//   scan -> 64-lane affine shuffle scan -> 16-wave LDS fold -> recompute with
//   exact incoming state -> coalesced store. Next chunk's global loads are
//   issued before the compute phase (latency hiding at 16 waves/CU).
// No workspace, no atomics, no inter-block sync (round 1 showed agent-scope
// flag sync costs ~hundreds of µs on non-coherent XCD L2s).

constexpr int kL = 65536;              // samples per channel
constexpr int kThr = 1024;             // threads per block = 16 waves
constexpr int kWaves = kThr / 64;      // 16
constexpr int kChunk = 16384;          // samples per chunk (64 KiB LDS)
constexpr int kPT = 16;                // samples per thread per chunk
constexpr int kNChunks = kL / kChunk;  // 4

// XOR swizzle: bank-balances both the chunk-strided (16/thread) and the
// linear float4 access patterns; bijective on pow2 ranges >= 256; keeps the
// float4 groups (index bits 0-1) intact.
__device__ __forceinline__ int swz(int i) {
    return i ^ (((i >> 5) & 7) << 2);
}

__global__ __launch_bounds__(kThr) void pink_channel(
    const float* __restrict__ white, float* __restrict__ pink)
{
    constexpr float A[6] = {0.99886f, 0.99332f, 0.969f, 0.8665f, 0.55f, -0.7616f};
    constexpr float C[6] = {0.0555179f, 0.0750759f, 0.153852f, 0.3104856f, 0.5329522f, -0.016898f};
    constexpr float B6G = 0.115926f, DIRECT = 0.5362f, OUTG = 0.11f;

    __shared__ __align__(16) float buf[kChunk];
    __shared__ float swv[6][kWaves];
    __shared__ float sLastW;             // last white sample of previous chunk

    const int tid = threadIdx.x, lane = tid & 63, wave = tid >> 6;
    const size_t chBase = (size_t)blockIdx.x * kL;

    // Constants: m16 = A^16, pmL = (A^16)^lane, Mwv = A^1024, cM = A^16384.
    // (Underflow to 0 for fast poles is numerically correct: those
    // contributions are genuinely negligible.)
    float m16[6], pmL[6], Mwv[6];
    #pragma unroll
    for (int p = 0; p < 6; ++p) {
        float q = A[p];
        #pragma unroll
        for (int i = 0; i < 4; ++i) q *= q;          // A^16
        m16[p] = q;
        float pm = 1.f, qq = q;
        #pragma unroll
        for (int b = 0; b < 6; ++b) { if ((lane >> b) & 1) pm *= qq; qq *= qq; }
        pmL[p] = pm;
        Mwv[p] = qq;                                  // (A^16)^64 = A^1024
    }

    if (tid == 0) sLastW = 0.f;

    float R[6] = {0.f, 0.f, 0.f, 0.f, 0.f, 0.f};      // channel state (uniform)

    // Preload chunk 0.
    float4 v[4];
    {
        const float4* src = (const float4*)(white + chBase);
        #pragma unroll
        for (int k = 0; k < 4; ++k) v[k] = src[tid + k * kThr];
    }

    for (int c = 0; c < kNChunks; ++c) {
        __syncthreads();                 // buf free again (and sLastW init on c=0)
        #pragma unroll
        for (int k = 0; k < 4; ++k)
            *(float4*)&buf[swz(4 * (tid + k * kThr))] = v[k];
        __syncthreads();                 // buf + sLastW (prev chunk) visible

        float w[kPT];
        #pragma unroll
        for (int kk = 0; kk < kPT / 4; ++kk) {
            float4 x = *(const float4*)&buf[swz(kPT * tid + 4 * kk)];
            w[4*kk] = x.x; w[4*kk+1] = x.y; w[4*kk+2] = x.z; w[4*kk+3] = x.w;
        }
        const float pwl = (tid == 0) ? sLastW : buf[swz(kPT * tid - 1)];

        // Issue next chunk's loads now: HBM latency hides under the scan math.
        if (c + 1 < kNChunks) {
            const float4* src =
                (const float4*)(white + chBase + (size_t)(c + 1) * kChunk);
            #pragma unroll
            for (int k = 0; k < 4; ++k) v[k] = src[tid + k * kThr];
        }

        // Local scan from zero init.
        float e[6] = {0.f, 0.f, 0.f, 0.f, 0.f, 0.f};
        #pragma unroll
        for (int k = 0; k < kPT; ++k) {
            const float ww = w[k];
            #pragma unroll
            for (int p = 0; p < 6; ++p) e[p] = fmaf(A[p], e[p], ww * C[p]);
        }

        // Intra-wave affine scan (constant per-round multiplier).
        float mk[6];
        #pragma unroll
        for (int p = 0; p < 6; ++p) mk[p] = m16[p];
        #pragma unroll
        for (int r = 0; r < 6; ++r) {
            const int off = 1 << r;
            float fe[6];
            #pragma unroll
            for (int p = 0; p < 6; ++p) fe[p] = __shfl_up(e[p], off);
            if (lane >= off) {
                #pragma unroll
                for (int p = 0; p < 6; ++p) e[p] = fmaf(mk[p], fe[p], e[p]);
            }
            #pragma unroll
            for (int p = 0; p < 6; ++p) mk[p] *= mk[p];
        }
        float ex[6];
        #pragma unroll
        for (int p = 0; p < 6; ++p) {
            ex[p] = __shfl_up(e[p], 1);
            if (lane == 0) ex[p] = 0.f;
        }
        if (lane == 63) {
            #pragma unroll
            for (int p = 0; p < 6; ++p) swv[p][wave] = e[p];
        }
        __syncthreads();                 // swv ready; all buf reads done

        // Fold channel state through the wave totals:
        //   Y walks R -> state after wave w2; snapshot X at this wave's start.
        float b[6];
        #pragma unroll
        for (int p = 0; p < 6; ++p) {
            float Y = R[p], X = R[p];
            #pragma unroll
            for (int w2 = 0; w2 < kWaves; ++w2) {
                if (w2 == wave) X = Y;
                Y = fmaf(Mwv[p], Y, swv[p][w2]);
            }
            b[p] = fmaf(pmL[p], X, ex[p]);
            R[p] = Y;                     // uniform: state at chunk end
        }
        float b6 = B6G * pwl;

        if (tid == kThr - 1) sLastW = w[kPT - 1];   // for next chunk's thread 0

        // Recompute with correct init; outputs overwrite inputs in buf.
        // (All reads of buf happened before the swv barrier — safe.)
        #pragma unroll
        for (int kk = 0; kk < kPT / 4; ++kk) {
            float4 o;
            float* op = &o.x;
            #pragma unroll
            for (int j = 0; j < 4; ++j) {
                const float ww = w[4*kk + j];
                #pragma unroll
                for (int p = 0; p < 6; ++p) b[p] = fmaf(A[p], b[p], ww * C[p]);
                const float sum = ((b[0]+b[1]) + (b[2]+b[3])) + ((b[4]+b[5]) + b6);
                op[j] = fmaf(DIRECT, ww, sum) * OUTG;
                b6 = B6G * ww;
            }
            *(float4*)&buf[swz(kPT * tid + 4 * kk)] = o;
        }
        __syncthreads();                 // outputs staged

        float4* dst = (float4*)(pink + chBase + (size_t)c * kChunk);
        #pragma unroll
        for (int k = 0; k < 4; ++k)
            dst[tid + k * kThr] = *(const float4*)&buf[swz(4 * (tid + k * kThr))];
    }
}

extern "C" void kernel_launch(void* const* d_in, const int* in_sizes, int n_in,
                              void* d_out, int out_size, void* d_ws, size_t ws_size,
                              hipStream_t stream) {
    const float* white = (const float*)d_in[0];
    float* pink = (float*)d_out;
    const int nCh = in_sizes[0] / kL;                 // 256 channels

    hipLaunchKernelGGL(pink_channel, dim3(nCh), dim3(kThr), 0, stream,
                       white, pink);
}

// Round 4
// 137.091 us; speedup vs baseline: 2.8082x; 2.1511x over previous
//
#include <hip/hip_runtime.h>

// Pink-noise 6-pole IIR — ONE kernel, one block per channel (B=256 = CU count).
// The sequential dependency never leaves the block: each block scans its
// channel in 8 chunks of 8192 samples, carrying the pole state in registers.
//   per chunk: coalesced float4 -> swizzled LDS transpose -> 16-sample local
//   scan -> 64-lane affine shuffle scan -> 8-wave LDS fold -> recompute with
//   exact incoming state -> coalesced store. Next chunk's global loads are
//   issued before the compute phase (latency hiding).
//
// __launch_bounds__(512, 2): 2 waves/EU = one 512-thread block per CU ->
// VGPR cap 256. Round 2 (1024 thr, default bounds) was capped at 64 VGPRs and
// spilled ~750 MB/dispatch of scratch traffic (FETCH 316 / WRITE 565 MB vs
// 128 MB ideal). Round 3's (1024, 4) config core-dumped — 512/2 gets the
// same register headroom via a different, smaller workgroup shape.

constexpr int kL = 65536;              // samples per channel
constexpr int kThr = 512;              // threads per block = 8 waves
constexpr int kWaves = kThr / 64;      // 8
constexpr int kChunk = kThr * 16;      // 8192 samples per chunk (32 KiB LDS)
constexpr int kPT = 16;                // samples per thread per chunk
constexpr int kNChunks = kL / kChunk;  // 8

// XOR swizzle: bank-balances both the chunk-strided (16/thread) and the
// linear float4 access patterns; bijective; keeps float4 groups (bits 0-1).
__device__ __forceinline__ int swz(int i) {
    return i ^ (((i >> 5) & 7) << 2);
}

__global__ __launch_bounds__(kThr, 2) void pink_channel(
    const float* __restrict__ white, float* __restrict__ pink)
{
    constexpr float A[6] = {0.99886f, 0.99332f, 0.969f, 0.8665f, 0.55f, -0.7616f};
    constexpr float C[6] = {0.0555179f, 0.0750759f, 0.153852f, 0.3104856f, 0.5329522f, -0.016898f};
    constexpr float B6G = 0.115926f, DIRECT = 0.5362f, OUTG = 0.11f;

    __shared__ __align__(16) float buf[kChunk];
    __shared__ float swv[6][kWaves];
    __shared__ float sLastW;             // last white sample of previous chunk

    const int tid = threadIdx.x, lane = tid & 63, wave = tid >> 6;
    const size_t chBase = (size_t)blockIdx.x * kL;

    // Constants: m16 = A^16, pmL = (A^16)^lane, Mwv = A^1024.
    // (Underflow to 0 for fast poles is numerically correct: those
    // contributions are genuinely negligible.)
    float m16[6], pmL[6], Mwv[6];
    #pragma unroll
    for (int p = 0; p < 6; ++p) {
        float q = A[p];
        #pragma unroll
        for (int i = 0; i < 4; ++i) q *= q;          // A^16
        m16[p] = q;
        float pm = 1.f, qq = q;
        #pragma unroll
        for (int b = 0; b < 6; ++b) { if ((lane >> b) & 1) pm *= qq; qq *= qq; }
        pmL[p] = pm;
        Mwv[p] = qq;                                  // (A^16)^64 = A^1024
    }

    if (tid == 0) sLastW = 0.f;

    float R[6] = {0.f, 0.f, 0.f, 0.f, 0.f, 0.f};      // channel state (uniform)

    // Preload chunk 0.
    float4 v[4];
    {
        const float4* src = (const float4*)(white + chBase);
        #pragma unroll
        for (int k = 0; k < 4; ++k) v[k] = src[tid + k * kThr];
    }

    for (int c = 0; c < kNChunks; ++c) {
        __syncthreads();                 // buf free again (and sLastW init on c=0)
        #pragma unroll
        for (int k = 0; k < 4; ++k)
            *(float4*)&buf[swz(4 * (tid + k * kThr))] = v[k];
        __syncthreads();                 // buf + sLastW (prev chunk) visible

        float w[kPT];
        #pragma unroll
        for (int kk = 0; kk < kPT / 4; ++kk) {
            float4 x = *(const float4*)&buf[swz(kPT * tid + 4 * kk)];
            w[4*kk] = x.x; w[4*kk+1] = x.y; w[4*kk+2] = x.z; w[4*kk+3] = x.w;
        }
        const float pwl = (tid == 0) ? sLastW : buf[swz(kPT * tid - 1)];

        // Issue next chunk's loads now: HBM latency hides under the scan math.
        if (c + 1 < kNChunks) {
            const float4* src =
                (const float4*)(white + chBase + (size_t)(c + 1) * kChunk);
            #pragma unroll
            for (int k = 0; k < 4; ++k) v[k] = src[tid + k * kThr];
        }

        // Local scan from zero init.
        float e[6] = {0.f, 0.f, 0.f, 0.f, 0.f, 0.f};
        #pragma unroll
        for (int k = 0; k < kPT; ++k) {
            const float ww = w[k];
            #pragma unroll
            for (int p = 0; p < 6; ++p) e[p] = fmaf(A[p], e[p], ww * C[p]);
        }

        // Intra-wave affine scan (constant per-round multiplier).
        float mk[6];
        #pragma unroll
        for (int p = 0; p < 6; ++p) mk[p] = m16[p];
        #pragma unroll
        for (int r = 0; r < 6; ++r) {
            const int off = 1 << r;
            float fe[6];
            #pragma unroll
            for (int p = 0; p < 6; ++p) fe[p] = __shfl_up(e[p], off);
            if (lane >= off) {
                #pragma unroll
                for (int p = 0; p < 6; ++p) e[p] = fmaf(mk[p], fe[p], e[p]);
            }
            #pragma unroll
            for (int p = 0; p < 6; ++p) mk[p] *= mk[p];
        }
        float ex[6];
        #pragma unroll
        for (int p = 0; p < 6; ++p) {
            ex[p] = __shfl_up(e[p], 1);
            if (lane == 0) ex[p] = 0.f;
        }
        if (lane == 63) {
            #pragma unroll
            for (int p = 0; p < 6; ++p) swv[p][wave] = e[p];
        }
        __syncthreads();                 // swv ready; all buf reads done

        // Fold channel state through the wave totals:
        //   Y walks R -> state after wave w2; snapshot X at this wave's start.
        float b[6];
        #pragma unroll
        for (int p = 0; p < 6; ++p) {
            float Y = R[p], X = R[p];
            #pragma unroll
            for (int w2 = 0; w2 < kWaves; ++w2) {
                if (w2 == wave) X = Y;
                Y = fmaf(Mwv[p], Y, swv[p][w2]);
            }
            b[p] = fmaf(pmL[p], X, ex[p]);
            R[p] = Y;                     // uniform: state at chunk end
        }
        float b6 = B6G * pwl;

        if (tid == kThr - 1) sLastW = w[kPT - 1];   // for next chunk's thread 0

        // Recompute with correct init; outputs overwrite inputs in buf.
        // (All reads of buf happened before the swv barrier — safe.)
        #pragma unroll
        for (int kk = 0; kk < kPT / 4; ++kk) {
            float4 o;
            float* op = &o.x;
            #pragma unroll
            for (int j = 0; j < 4; ++j) {
                const float ww = w[4*kk + j];
                #pragma unroll
                for (int p = 0; p < 6; ++p) b[p] = fmaf(A[p], b[p], ww * C[p]);
                const float sum = ((b[0]+b[1]) + (b[2]+b[3])) + ((b[4]+b[5]) + b6);
                op[j] = fmaf(DIRECT, ww, sum) * OUTG;
                b6 = B6G * ww;
            }
            *(float4*)&buf[swz(kPT * tid + 4 * kk)] = o;
        }
        __syncthreads();                 // outputs staged

        float4* dst = (float4*)(pink + chBase + (size_t)c * kChunk);
        #pragma unroll
        for (int k = 0; k < 4; ++k)
            dst[tid + k * kThr] = *(const float4*)&buf[swz(4 * (tid + k * kThr))];
    }
}

extern "C" void kernel_launch(void* const* d_in, const int* in_sizes, int n_in,
                              void* d_out, int out_size, void* d_ws, size_t ws_size,
                              hipStream_t stream) {
    const float* white = (const float*)d_in[0];
    float* pink = (float*)d_out;
    const int nCh = in_sizes[0] / kL;                 // 256 channels

    hipLaunchKernelGGL(pink_channel, dim3(nCh), dim3(kThr), 0, stream,
                       white, pink);
}